// Round 2
// baseline (677.028 us; speedup 1.0000x reference)
//
#include <hip/hip_runtime.h>
#include <hip/hip_fp16.h>

#define DB    768
#define SEQ   2048
#define BATCH 8
#define NTOK  (BATCH*SEQ)      // 16384
#define NFUSE (3*DB)           // 2304 fused QKV output columns
#define NORM_F 0.036084391824351613f

typedef __attribute__((ext_vector_type(8))) short  short8;
typedef __attribute__((ext_vector_type(4))) short  short4v;
typedef __attribute__((ext_vector_type(4))) float  f32x4;
typedef __attribute__((ext_vector_type(4))) float  float4v;
typedef unsigned int u32;

__device__ __forceinline__ unsigned short f2bf(float f) {
  unsigned int u = __float_as_uint(f);
  u += 0x7fffu + ((u >> 16) & 1u);
  return (unsigned short)(u >> 16);
}
__device__ __forceinline__ float bf2f(unsigned short h) {
  return __uint_as_float(((unsigned int)h) << 16);
}
__device__ __forceinline__ float h2f_bits(unsigned short h) {
  __half v; __builtin_memcpy(&v, &h, 2); return __half2float(v);
}
__device__ __forceinline__ unsigned short f2h_bits(float f) {
  __half v = __float2half(f); unsigned short u; __builtin_memcpy(&u, &v, 2); return u;
}

// async global->LDS, 16B per lane. LDS dest = wave-uniform base + lane*16.
__device__ __forceinline__ void glds16(const unsigned short* g, void* l) {
  __builtin_amdgcn_global_load_lds(
      (const __attribute__((address_space(1))) u32*)(const void*)g,
      (__attribute__((address_space(3))) u32*)l, 16, 0, 0);
}

// Chunk-major 128x32 bf16 tile in LDS: element (row, c*8+e) at short index
// c*1024 + row*8 + e.  glds-linear (byte p: c=p>>11, row=(p>>4)&127) and
// conflict-free ds_read_b128 frag reads (8 consecutive lanes cover 32 banks).

// =============================================================================
// wsplit: W[d][n] (3 weights) -> fused WT[nf][d] bf16 hi/lo, via LDS transpose.
// grid 432 = 3 * (768/64)^2
// =============================================================================
__global__ __launch_bounds__(256) void wsplit_kernel(
    const float* __restrict__ Wq, const float* __restrict__ Wk,
    const float* __restrict__ Wv,
    unsigned short* __restrict__ WTh, unsigned short* __restrict__ WTl) {
  __shared__ float T[64][68];
  int bx = blockIdx.x;
  int w = bx / 144, rem = bx % 144;
  int d0 = (rem / 12) * 64, n0 = (rem % 12) * 64;
  const float* W = (w == 0) ? Wq : ((w == 1) ? Wk : Wv);
  int t = threadIdx.x;
  int dl = t >> 4, n4 = (t & 15) * 4;
#pragma unroll
  for (int j = 0; j < 4; j++) {
    float4v v = *(const float4v*)(W + (size_t)(d0 + dl + j * 16) * DB + n0 + n4);
    *(float4v*)&T[dl + j * 16][n4] = v;
  }
  __syncthreads();
  int nl = t >> 2, dc = (t & 3) * 16;
  short8 hb[2], lb[2];
#pragma unroll
  for (int e = 0; e < 16; e++) {
    float v = T[dc + e][nl];
    unsigned short h = f2bf(v);
    hb[e >> 3][e & 7] = (short)h;
    lb[e >> 3][e & 7] = (short)f2bf(v - bf2f(h));
  }
  size_t o = ((size_t)w * DB + n0 + nl) * DB + d0 + dc;
  *(short8*)(WTh + o) = hb[0]; *(short8*)(WTh + o + 8) = hb[1];
  *(short8*)(WTl + o) = lb[0]; *(short8*)(WTl + o + 8) = lb[1];
}

// =============================================================================
// xsplit: X fp32 -> Xh/Xl bf16, once.  grid 12288
// =============================================================================
__global__ __launch_bounds__(256) void xsplit_kernel(
    const float* __restrict__ X,
    unsigned short* __restrict__ Xh, unsigned short* __restrict__ Xl) {
  size_t i4 = ((size_t)blockIdx.x * 256 + threadIdx.x) * 4;
  float4v v = *(const float4v*)(X + i4);
  short4v h, l;
#pragma unroll
  for (int j = 0; j < 4; j++) {
    unsigned short hh = f2bf(v[j]);
    h[j] = (short)hh;
    l[j] = (short)f2bf(v[j] - bf2f(hh));
  }
  *(short4v*)(Xh + i4) = h;
  *(short4v*)(Xl + i4) = l;
}

// =============================================================================
// compact: per batch, list of unmasked q indices (ascending) + count.
// =============================================================================
__global__ __launch_bounds__(256) void compact_kernel(
    const int* __restrict__ mask, int* __restrict__ idx, int* __restrict__ cnt) {
  int b = blockIdx.x, t = threadIdx.x;
  const int* m = mask + b * SEQ;
  __shared__ int pref[256];
  int mv[8], c = 0, base = t * 8;
#pragma unroll
  for (int j = 0; j < 8; j++) { mv[j] = (m[base + j] != 0); c += mv[j]; }
  pref[t] = c;
  __syncthreads();
  for (int off = 1; off < 256; off <<= 1) {
    int add = (t >= off) ? pref[t - off] : 0;
    __syncthreads();
    pref[t] += add;
    __syncthreads();
  }
  int o = pref[t] - c;
  int* ib = idx + b * SEQ;
#pragma unroll
  for (int j = 0; j < 8; j++) if (mv[j]) ib[o++] = base + j;
  if (t == 255) cnt[b] = pref[255];
}

// =============================================================================
// proj: fused QKV GEMM.  C[m, nf] = X[m,:] @ Wall[:,nf] + bias, nf in [0,2304).
// 128x128 tile, BK=32, glds staging, split-bf16 3-MFMA.
// z = nf/768 is block-uniform (768 % 128 == 0).
// =============================================================================
__global__ __launch_bounds__(256) void proj_kernel(
    const unsigned short* __restrict__ Xh, const unsigned short* __restrict__ Xl,
    const unsigned short* __restrict__ WTh, const unsigned short* __restrict__ WTl,
    const float* __restrict__ bq, const float* __restrict__ bk,
    const float* __restrict__ bv,
    unsigned short* __restrict__ Qh, unsigned short* __restrict__ Ql,
    unsigned short* __restrict__ Kh, unsigned short* __restrict__ Kl,
    unsigned short* __restrict__ VT) {
  __shared__ __align__(16) unsigned short Ash[4096], Asl[4096], Bsh[4096], Bsl[4096];
  int n0 = blockIdx.x << 7;
  int m0 = blockIdx.y << 7;
  int tid = threadIdx.x;
  int wave = tid >> 6, lane = tid & 63;
  int wm = wave & 1, wn = wave >> 1;
  int quad = lane >> 4, l16 = lane & 15;
  int srow = ((wave & 1) << 6) | lane;     // staged row (0..127)
  int coff = (wave >> 1) * 8;              // chunk elem offset for issue 0

  const unsigned short* pAh = Xh + (size_t)(m0 + srow) * DB + coff;
  const unsigned short* pAl = Xl + (size_t)(m0 + srow) * DB + coff;
  const unsigned short* pBh = WTh + (size_t)(n0 + srow) * DB + coff;
  const unsigned short* pBl = WTl + (size_t)(n0 + srow) * DB + coff;
  char* lAh = (char*)Ash + wave * 1024;
  char* lAl = (char*)Asl + wave * 1024;
  char* lBh = (char*)Bsh + wave * 1024;
  char* lBl = (char*)Bsl + wave * 1024;

  f32x4 acc[4][4];
#pragma unroll
  for (int mi = 0; mi < 4; mi++)
#pragma unroll
    for (int ni = 0; ni < 4; ni++) acc[mi][ni] = (f32x4){0.f, 0.f, 0.f, 0.f};

  for (int kt = 0; kt < DB; kt += 32) {
    glds16(pAh + kt, lAh);      glds16(pAh + kt + 16, lAh + 4096);
    glds16(pAl + kt, lAl);      glds16(pAl + kt + 16, lAl + 4096);
    glds16(pBh + kt, lBh);      glds16(pBh + kt + 16, lBh + 4096);
    glds16(pBl + kt, lBl);      glds16(pBl + kt + 16, lBl + 4096);
    __builtin_amdgcn_s_waitcnt(0);
    __syncthreads();

    short8 afh[4], afl[4], bfh[4], bfl[4];
#pragma unroll
    for (int mi = 0; mi < 4; mi++) {
      int r = wm * 64 + mi * 16 + l16;
      afh[mi] = *(const short8*)&Ash[quad * 1024 + r * 8];
      afl[mi] = *(const short8*)&Asl[quad * 1024 + r * 8];
    }
#pragma unroll
    for (int ni = 0; ni < 4; ni++) {
      int r = wn * 64 + ni * 16 + l16;
      bfh[ni] = *(const short8*)&Bsh[quad * 1024 + r * 8];
      bfl[ni] = *(const short8*)&Bsl[quad * 1024 + r * 8];
    }
#pragma unroll
    for (int mi = 0; mi < 4; mi++)
#pragma unroll
      for (int ni = 0; ni < 4; ni++) {
        acc[mi][ni] = __builtin_amdgcn_mfma_f32_16x16x32_bf16(afh[mi], bfh[ni], acc[mi][ni], 0, 0, 0);
        acc[mi][ni] = __builtin_amdgcn_mfma_f32_16x16x32_bf16(afh[mi], bfl[ni], acc[mi][ni], 0, 0, 0);
        acc[mi][ni] = __builtin_amdgcn_mfma_f32_16x16x32_bf16(afl[mi], bfh[ni], acc[mi][ni], 0, 0, 0);
      }
    __syncthreads();
  }

  int z = n0 / DB;                 // 0=Q 1=K 2=V, block-uniform
  int nl0 = n0 - z * DB;
  const float* bias = (z == 0) ? bq : ((z == 1) ? bk : bv);
#pragma unroll
  for (int mi = 0; mi < 4; mi++)
#pragma unroll
    for (int ni = 0; ni < 4; ni++)
#pragma unroll
      for (int r = 0; r < 4; r++) {
        int gm = m0 + wm * 64 + mi * 16 + quad * 4 + r;
        int ln = nl0 + wn * 64 + ni * 16 + l16;
        float val = acc[mi][ni][r] + bias[ln];
        unsigned short h = f2bf(val);
        if (z == 0) {
          Qh[(size_t)gm * DB + ln] = h;
          Ql[(size_t)gm * DB + ln] = f2bf(val - bf2f(h));
        } else if (z == 1) {
          Kh[(size_t)gm * DB + ln] = h;
          Kl[(size_t)gm * DB + ln] = f2bf(val - bf2f(h));
        } else {
          int bb = gm >> 11, s = gm & 2047;
          VT[((size_t)bb * DB + ln) * SEQ + s] = h;
        }
      }
}

// =============================================================================
// vmean: Vmean[b][n] = mean_s VT[b][n][s].  grid 6144
// =============================================================================
__global__ __launch_bounds__(256) void vmean_kernel(
    const unsigned short* __restrict__ VT, float* __restrict__ Vmean) {
  int bn = blockIdx.x;
  const unsigned short* p = VT + (size_t)bn * SEQ;
  int t = threadIdx.x, wave = t >> 6, lane = t & 63;
  short8 hv = *(const short8*)(p + t * 8);
  float s = 0.f;
#pragma unroll
  for (int j = 0; j < 8; j++) s += bf2f((unsigned short)hv[j]);
#pragma unroll
  for (int off = 32; off >= 1; off >>= 1) s += __shfl_down(s, off);
  __shared__ float red[4];
  if (lane == 0) red[wave] = s;
  __syncthreads();
  if (t == 0) Vmean[bn] = (red[0] + red[1] + red[2] + red[3]) * (1.0f / SEQ);
}

// =============================================================================
// scores (compacted q rows): SC[b][qc][t] = Q[idx[qc]] . K[t], fp16.
// =============================================================================
__global__ __launch_bounds__(256) void scores_kernel(
    const unsigned short* __restrict__ Qh, const unsigned short* __restrict__ Ql,
    const unsigned short* __restrict__ Kh, const unsigned short* __restrict__ Kl,
    const int* __restrict__ idx, const int* __restrict__ cnt,
    unsigned short* __restrict__ SC) {
  __shared__ __align__(16) unsigned short Ash[4096], Asl[4096], Bsh[4096], Bsl[4096];
  int b = blockIdx.z;
  int cb = cnt[b];
  int q0 = blockIdx.y << 7;
  if (q0 >= cb) return;
  int t0 = blockIdx.x << 7;
  int tid = threadIdx.x;
  int wave = tid >> 6, lane = tid & 63;
  int wm = wave & 1, wn = wave >> 1;
  int quad = lane >> 4, l16 = lane & 15;
  int srow = ((wave & 1) << 6) | lane;
  int coff = (wave >> 1) * 8;

  int qr = q0 + srow; if (qr >= cb) qr = cb - 1;   // clamp tail (dup rows, writes guarded)
  int gq = idx[b * SEQ + qr];
  const unsigned short* pAh = Qh + ((size_t)b * SEQ + gq) * DB + coff;
  const unsigned short* pAl = Ql + ((size_t)b * SEQ + gq) * DB + coff;
  const unsigned short* pBh = Kh + ((size_t)b * SEQ + t0 + srow) * DB + coff;
  const unsigned short* pBl = Kl + ((size_t)b * SEQ + t0 + srow) * DB + coff;
  char* lAh = (char*)Ash + wave * 1024;
  char* lAl = (char*)Asl + wave * 1024;
  char* lBh = (char*)Bsh + wave * 1024;
  char* lBl = (char*)Bsl + wave * 1024;

  f32x4 acc[4][4];
#pragma unroll
  for (int mi = 0; mi < 4; mi++)
#pragma unroll
    for (int ni = 0; ni < 4; ni++) acc[mi][ni] = (f32x4){0.f, 0.f, 0.f, 0.f};

  for (int kt = 0; kt < DB; kt += 32) {
    glds16(pAh + kt, lAh);      glds16(pAh + kt + 16, lAh + 4096);
    glds16(pAl + kt, lAl);      glds16(pAl + kt + 16, lAl + 4096);
    glds16(pBh + kt, lBh);      glds16(pBh + kt + 16, lBh + 4096);
    glds16(pBl + kt, lBl);      glds16(pBl + kt + 16, lBl + 4096);
    __builtin_amdgcn_s_waitcnt(0);
    __syncthreads();

    short8 afh[4], afl[4], bfh[4], bfl[4];
#pragma unroll
    for (int mi = 0; mi < 4; mi++) {
      int r = wm * 64 + mi * 16 + l16;
      afh[mi] = *(const short8*)&Ash[quad * 1024 + r * 8];
      afl[mi] = *(const short8*)&Asl[quad * 1024 + r * 8];
    }
#pragma unroll
    for (int ni = 0; ni < 4; ni++) {
      int r = wn * 64 + ni * 16 + l16;
      bfh[ni] = *(const short8*)&Bsh[quad * 1024 + r * 8];
      bfl[ni] = *(const short8*)&Bsl[quad * 1024 + r * 8];
    }
#pragma unroll
    for (int mi = 0; mi < 4; mi++)
#pragma unroll
      for (int ni = 0; ni < 4; ni++) {
        acc[mi][ni] = __builtin_amdgcn_mfma_f32_16x16x32_bf16(afh[mi], bfh[ni], acc[mi][ni], 0, 0, 0);
        acc[mi][ni] = __builtin_amdgcn_mfma_f32_16x16x32_bf16(afh[mi], bfl[ni], acc[mi][ni], 0, 0, 0);
        acc[mi][ni] = __builtin_amdgcn_mfma_f32_16x16x32_bf16(afl[mi], bfh[ni], acc[mi][ni], 0, 0, 0);
      }
    __syncthreads();
  }

#pragma unroll
  for (int mi = 0; mi < 4; mi++)
#pragma unroll
    for (int r = 0; r < 4; r++) {
      int qc = q0 + wm * 64 + mi * 16 + quad * 4 + r;
      if (qc < cb) {
#pragma unroll
        for (int ni = 0; ni < 4; ni++) {
          int gt = t0 + wn * 64 + ni * 16 + l16;
          SC[((size_t)b * SEQ + qc) * SEQ + gt] = f2h_bits(acc[mi][ni][r]);
        }
      }
    }
}

// =============================================================================
// softmax on compacted rows, fp16 -> bf16 * NORM in place.
// =============================================================================
__global__ __launch_bounds__(256) void softmax_kernel(
    unsigned short* __restrict__ SC, const int* __restrict__ cnt) {
  int b = blockIdx.x >> 11, qc = blockIdx.x & 2047;
  if (qc >= cnt[b]) return;
  unsigned short* p = SC + ((size_t)b * SEQ + qc) * SEQ;
  int tid = threadIdx.x;

  short8 hv = *(const short8*)(p + (tid << 3));
  float v[8];
#pragma unroll
  for (int j = 0; j < 8; j++) v[j] = h2f_bits((unsigned short)hv[j]);

  float m = v[0];
#pragma unroll
  for (int j = 1; j < 8; j++) m = fmaxf(m, v[j]);
#pragma unroll
  for (int off = 32; off >= 1; off >>= 1) m = fmaxf(m, __shfl_down(m, off));

  __shared__ float red[8];
  int w = tid >> 6;
  if ((tid & 63) == 0) red[w] = m;
  __syncthreads();
  m = fmaxf(fmaxf(red[0], red[1]), fmaxf(red[2], red[3]));

  float e[8], s = 0.f;
#pragma unroll
  for (int j = 0; j < 8; j++) { e[j] = __expf(v[j] - m); s += e[j]; }
#pragma unroll
  for (int off = 32; off >= 1; off >>= 1) s += __shfl_down(s, off);
  if ((tid & 63) == 0) red[4 + w] = s;
  __syncthreads();
  float L = red[4] + red[5] + red[6] + red[7];

  float scale = NORM_F / L;
  short8 ov;
#pragma unroll
  for (int j = 0; j < 8; j++) ov[j] = (short)f2bf(e[j] * scale);
  *(short8*)(p + (tid << 3)) = ov;
}

// =============================================================================
// fill: masked rows get NORM * mean(V).  grid NTOK, early-exit on unmasked.
// =============================================================================
__global__ __launch_bounds__(256) void fill_kernel(
    const int* __restrict__ mask, const float* __restrict__ Vmean,
    float* __restrict__ out) {
  int row = blockIdx.x;
  if (mask[row] != 0) return;
  const float* vm = Vmean + (row >> 11) * DB;
  float* o = out + (size_t)row * DB;
  for (int n = threadIdx.x; n < DB; n += 256) o[n] = vm[n] * NORM_F;
}

// =============================================================================
// pv (compacted rows): out[idx[qc]][v] = sum_t attn[qc][t] * V[t][v]
// =============================================================================
__global__ __launch_bounds__(256) void pv_kernel(
    const unsigned short* __restrict__ SC, const unsigned short* __restrict__ VT,
    const int* __restrict__ idx, const int* __restrict__ cnt,
    float* __restrict__ out) {
  __shared__ __align__(16) unsigned short Ash[4096], Bsh[4096];
  int b = blockIdx.z;
  int cb = cnt[b];
  int q0 = blockIdx.y << 7;
  if (q0 >= cb) return;
  int v0 = blockIdx.x << 7;
  int tid = threadIdx.x;
  int wave = tid >> 6, lane = tid & 63;
  int wm = wave & 1, wn = wave >> 1;
  int quad = lane >> 4, l16 = lane & 15;
  int srow = ((wave & 1) << 6) | lane;
  int coff = (wave >> 1) * 8;

  const unsigned short* pA = SC + ((size_t)b * SEQ + q0 + srow) * SEQ + coff;  // tail rows: poison, writes guarded
  const unsigned short* pB = VT + ((size_t)b * DB + v0 + srow) * SEQ + coff;
  char* lA = (char*)Ash + wave * 1024;
  char* lB = (char*)Bsh + wave * 1024;

  f32x4 acc[4][4];
#pragma unroll
  for (int mi = 0; mi < 4; mi++)
#pragma unroll
    for (int ni = 0; ni < 4; ni++) acc[mi][ni] = (f32x4){0.f, 0.f, 0.f, 0.f};

  for (int kt = 0; kt < SEQ; kt += 32) {
    glds16(pA + kt, lA);      glds16(pA + kt + 16, lA + 4096);
    glds16(pB + kt, lB);      glds16(pB + kt + 16, lB + 4096);
    __builtin_amdgcn_s_waitcnt(0);
    __syncthreads();

    short8 af[4], bf[4];
#pragma unroll
    for (int mi = 0; mi < 4; mi++)
      af[mi] = *(const short8*)&Ash[quad * 1024 + (wm * 64 + mi * 16 + l16) * 8];
#pragma unroll
    for (int ni = 0; ni < 4; ni++)
      bf[ni] = *(const short8*)&Bsh[quad * 1024 + (wn * 64 + ni * 16 + l16) * 8];
#pragma unroll
    for (int mi = 0; mi < 4; mi++)
#pragma unroll
      for (int ni = 0; ni < 4; ni++)
        acc[mi][ni] = __builtin_amdgcn_mfma_f32_16x16x32_bf16(af[mi], bf[ni], acc[mi][ni], 0, 0, 0);
    __syncthreads();
  }

#pragma unroll
  for (int mi = 0; mi < 4; mi++)
#pragma unroll
    for (int r = 0; r < 4; r++) {
      int qc = q0 + wm * 64 + mi * 16 + quad * 4 + r;
      if (qc < cb) {
        int q = idx[b * SEQ + qc];
#pragma unroll
        for (int ni = 0; ni < 4; ni++) {
          int gv = v0 + wn * 64 + ni * 16 + l16;
          out[((size_t)b * SEQ + q) * DB + gv] = acc[mi][ni][r];
        }
      }
    }
}

// =============================================================================
extern "C" void kernel_launch(void* const* d_in, const int* in_sizes, int n_in,
                              void* d_out, int out_size, void* d_ws, size_t ws_size,
                              hipStream_t stream) {
  const float* x    = (const float*)d_in[0];
  const int*   mask = (const int*)d_in[1];
  const float* Wq   = (const float*)d_in[2];
  const float* bq   = (const float*)d_in[3];
  const float* Wk   = (const float*)d_in[4];
  const float* bk   = (const float*)d_in[5];
  const float* Wv   = (const float*)d_in[6];
  const float* bv   = (const float*)d_in[7];
  float* out = (float*)d_out;
  char* ws = (char*)d_ws;

  // Workspace (~184 MB). SC region [0, 67.1MB) is reused: Xh/Xl/WTh/WTl live
  // there only until proj completes; scores then overwrites it with SC.
  const size_t TOK2 = (size_t)NTOK * DB * 2;                 // 25,165,824 B
  unsigned short* SC  = (unsigned short*)ws;
  unsigned short* Xh  = (unsigned short*)ws;
  unsigned short* Xl  = (unsigned short*)(ws + TOK2);
  unsigned short* WTh = (unsigned short*)(ws + 2 * TOK2);                   // 50.3 MB
  unsigned short* WTl = (unsigned short*)(ws + 2 * TOK2 + (size_t)NFUSE * DB * 2);
  const size_t SCSZ = (size_t)BATCH * SEQ * SEQ * 2;         // 67,108,864 B
  unsigned short* Qh = (unsigned short*)(ws + SCSZ);
  unsigned short* Ql = Qh + (size_t)NTOK * DB;
  unsigned short* Kh = Ql + (size_t)NTOK * DB;
  unsigned short* Kl = Kh + (size_t)NTOK * DB;
  unsigned short* VT = Kl + (size_t)NTOK * DB;
  int*   idx   = (int*)(ws + SCSZ + 5 * TOK2);
  int*   cnt   = idx + NTOK;
  float* Vmean = (float*)(cnt + 16);

  wsplit_kernel<<<432, 256, 0, stream>>>(Wq, Wk, Wv, WTh, WTl);
  xsplit_kernel<<<NTOK * DB / 1024, 256, 0, stream>>>(x, Xh, Xl);
  compact_kernel<<<BATCH, 256, 0, stream>>>(mask, idx, cnt);
  proj_kernel<<<dim3(NFUSE / 128, NTOK / 128), 256, 0, stream>>>(
      Xh, Xl, WTh, WTl, bq, bk, bv, Qh, Ql, Kh, Kl, VT);
  vmean_kernel<<<BATCH * DB, 256, 0, stream>>>(VT, Vmean);
  scores_kernel<<<dim3(SEQ / 128, SEQ / 128, BATCH), 256, 0, stream>>>(
      Qh, Ql, Kh, Kl, idx, cnt, SC);
  softmax_kernel<<<NTOK, 256, 0, stream>>>(SC, cnt);
  fill_kernel<<<NTOK, 256, 0, stream>>>(mask, Vmean, out);
  pv_kernel<<<dim3(DB / 128, SEQ / 128, BATCH), 256, 0, stream>>>(
      SC, VT, idx, cnt, out);
}